// Round 1
// baseline (62.207 us; speedup 1.0000x reference)
//
#include <hip/hip_runtime.h>

// y[i,o,n] = sum_{j,k} x[j,(o-1)%28,n+k-1]*W[i,j,0,k] + x[j,(o-2)%28,n+k-1]*W[i,j,1,k]
// x: (64,28,28) f32, W: (128,64,2,3) f32, y: (128,28,28) f32
//
// Scatter-accumulator form: thread n loads x[.,.,n] and accumulates
// contributions to y[n+1] (A0), y[n] (A1), y[n-1] (A2); two epilogue
// shuffles resolve the n+-1 taps. i = bid>>2 is block-uniform -> W reads
// scalarize to s_load.
//
// R3: the kernel was latency-bound, not throughput-bound (1 block/CU,
// 1.75 waves/SIMD, 64-iteration load-latency chain). Split the j=64
// reduction 4-ways across thread groups (block 896 = 4 jg x 224) and
// the o range into quarters (grid 512 = 128 i x 4 q): j-loop is 16
// iters fully unrolled (single load epoch), occupancy ~7 waves/SIMD,
// one 8KB LDS tree-reduce at the end.

#define BLOCK 896

__global__ __launch_bounds__(BLOCK, 1)
void conv_shift_kernel(const float* __restrict__ x,
                       const float* __restrict__ W,
                       float* __restrict__ out) {
    const int bid = blockIdx.x;
    const int i = bid >> 2;           // output channel, uniform per block
    const int q = bid & 3;            // o-quarter (7 rows each)
    const int tid = threadIdx.x;
    const int n  = tid & 31;          // column; active when n < 28
    const int rr = tid >> 5;          // 0..27
    const int o_local = rr % 7;       // 0..6
    const int g  = rr / 7;            // j-group 0..3 (16 j each)
    const int o  = q * 7 + o_local;
    const int oa = (o + 27) % 28;     // row for l=0 taps
    const int ob = (o + 26) % 28;     // row for l=1 taps
    const bool act = (n < 28);
    const int nc = act ? n : 0;       // clamp: inactive lanes load in-bounds garbage

    const float* __restrict__ xa = x + g * (16 * 784) + oa * 28 + nc;
    const float* __restrict__ xb = x + g * (16 * 784) + ob * 28 + nc;
    const float* __restrict__ wp = W + i * 384 + g * 96;  // 16 j x 6 floats

    float A0 = 0.f, A1 = 0.f, A2 = 0.f;   // dest n+1 / n / n-1
    #pragma unroll
    for (int j = 0; j < 16; ++j) {
        const float va = xa[j * 784];
        const float vb = xb[j * 784];

        const float w0 = wp[j*6+0], w1 = wp[j*6+1], w2 = wp[j*6+2];
        const float w3 = wp[j*6+3], w4 = wp[j*6+4], w5 = wp[j*6+5];

        A0 += w0 * va + w3 * vb;   // x[n] -> y[n+1] (k=0 weights)
        A1 += w1 * va + w4 * vb;   // center tap
        A2 += w2 * va + w5 * vb;   // x[n] -> y[n-1] (k=2 weights)
    }

    // Cross-group reduction: groups 1..3 park partials in LDS, group 0 sums.
    __shared__ float red[3][3][224];       // [g-1][acc][o_local*32+n]
    const int slot = o_local * 32 + n;     // 0..223, stride-1 across lanes
    if (g != 0) {
        red[g-1][0][slot] = A0;
        red[g-1][1][slot] = A1;
        red[g-1][2][slot] = A2;
    }
    __syncthreads();

    if (g == 0) {
        A0 += red[0][0][slot] + red[1][0][slot] + red[2][0][slot];
        A1 += red[0][1][slot] + red[1][1][slot] + red[2][1][slot];
        A2 += red[0][2][slot] + red[1][2][slot] + red[2][2][slot];

        // y[n] = A1[n] + A0[n-1] + A2[n+1]
        float up = __shfl_up(A0, 1, 32);
        if (n == 0) up = 0.f;                // left zero-pad
        float dn = __shfl_down(A2, 1, 32);
        if (n == 27) dn = 0.f;               // right zero-pad (lane 28 holds garbage)

        if (act) {
            out[i * 784 + o * 28 + n] = A1 + up + dn;
        }
    }
}

extern "C" void kernel_launch(void* const* d_in, const int* in_sizes, int n_in,
                              void* d_out, int out_size, void* d_ws, size_t ws_size,
                              hipStream_t stream) {
    const float* x = (const float*)d_in[0];   // 64*28*28
    const float* W = (const float*)d_in[1];   // 128*64*2*3
    float* out = (float*)d_out;               // 128*28*28
    conv_shift_kernel<<<512, BLOCK, 0, stream>>>(x, W, out);
}